// Round 8
// baseline (319.822 us; speedup 1.0000x reference)
//
#include <hip/hip_runtime.h>

// Problem constants (fixed by the reference module)
#define K_   64
#define C_   64
#define W_   128
#define P_   4
#define B_   16
#define W2_  136                 // W + 2*PAD
#define OUTSP 18496              // W2*W2 elements per (k,c) plane
#define CWW  1048576             // C*W*W — cube stride per face (k index)

// Phased execution: phase p streams cube faces [32p, 32p+32) (134 MB, fits
// L3) and performs exactly the halo gathers whose TARGET face is in that
// half (f==-1 zeros are written in phase 0). Gathers then hit L3 lines
// brought in by the same-phase stream (or prefetch them for it).
//
// Per phase, work in 4-float quads grouped into 64-quad wave units:
//  interior: 8,388,608 quads = 131,072 units
//  halo    : 2,162,688 quads =  33,792 units (revisited each phase, filtered)
// Unit map U -> (g=U/5, r=U%5): r<4 -> interior unit g*4+r (guard), r==4 ->
// halo unit g. 4:1 interleave keeps gathers flowing alongside the stream.
#define NQ_TB     1114112
#define NQ_HALO   2162688
#define NU_INT_PH 131072
#define NU_HALO_U 33792
#define N_UNITS_PH (NU_HALO_U * 5)     // 168,960
#define N_WID_PH   (N_UNITS_PH * 64)   // 10,813,440

typedef int   int4n   __attribute__((ext_vector_type(4)));
typedef float float4n __attribute__((ext_vector_type(4)));

__global__ void fused_pad_phase_kernel(const float* __restrict__ cube,
                                       const int* __restrict__ to_process,
                                       const int* __restrict__ px_tb,
                                       const int* __restrict__ px_lr,
                                       const int* __restrict__ fi_tb,
                                       const int* __restrict__ fi_lr,
                                       float* __restrict__ out,
                                       int phase) {
    __shared__ int inv[6 * B_];   // global face id -> cube row, -1 absent
    __shared__ int tp[K_];
    const int tid = threadIdx.x;
    if (tid < 6 * B_) inv[tid] = -1;
    if (tid < K_)     tp[tid]  = to_process[tid];
    __syncthreads();
    if (tid < K_)     inv[tp[tid]] = tid;
    __syncthreads();

    const int stride = gridDim.x * blockDim.x;
    for (int t = blockIdx.x * blockDim.x + tid; t < N_WID_PH; t += stride) {
        int U = t >> 6;            // wave unit (uniform across wave)
        int l = t & 63;            // lane
        int g = U / 5;
        int r = U - 5 * g;

        if (r < 4) {
            // ---- interior copy unit (this phase's cube half) ----
            int iu = (g << 2) + r;
            if (iu < NU_INT_PH) {
                int id = (phase << 23) + (iu << 6) + l;   // global quad id
                int q  = id & 31;
                int R  = id >> 5;
                int rr = R & (W_ - 1);
                int kc = R >> 7;
                float4n v = reinterpret_cast<const float4n*>(cube)[id];
                float4n* dst = reinterpret_cast<float4n*>(
                    out + (size_t)kc * OUTSP + (size_t)(rr + P_) * W2_ + P_) + q;
                __builtin_nontemporal_store(v, dst);
            }
        } else {
            // ---- halo unit, ownership-filtered by target face half ----
            int hq = (g << 6) + l;
            if (hq < NQ_TB) {
                // top/bottom: 4 cols per thread
                int col4 = hq % 34;
                int rest = hq / 34;
                int rr   = rest & 7;
                int cc   = (rest >> 3) & 63;
                int kk   = rest >> 9;

                int gf = tp[kk];
                int b6 = 6 * (gf / 6);
                int fb = gf - b6;
                int4n fiv = *reinterpret_cast<const int4n*>(
                    fi_tb + (fb * 2 * P_ + rr) * W2_ + col4 * 4);
                int4n pxv = *reinterpret_cast<const int4n*>(
                    px_tb + ((fb * C_ + cc) * 2 * P_ + rr) * W2_ + col4 * 4);

                int outr = (rr < P_) ? rr : (W_ + rr);
                float* obase = out + (size_t)(kk * C_ + cc) * OUTSP
                                   + (size_t)outr * W2_ + col4 * 4;
#pragma unroll
                for (int e = 0; e < 4; ++e) {
                    int fe = inv[((const int*)&fiv)[e] + b6];
                    bool own = (fe < 0) ? (phase == 0) : ((fe >> 5) == phase);
                    if (own) {
                        float v = (fe >= 0)
                            ? cube[(size_t)fe * CWW + ((const int*)&pxv)[e]] : 0.0f;
                        __builtin_nontemporal_store(v, obase + e);
                    }
                }
            } else {
                // left/right: 4 cols (one side) per thread
                int u  = hq - NQ_TB;
                int q  = u & 1;
                int rr = (u >> 1) & (W_ - 1);
                int cc = (u >> 8) & 63;
                int kk = u >> 14;

                int gf = tp[kk];
                int b6 = 6 * (gf / 6);
                int fb = gf - b6;
                int4n fiv = *reinterpret_cast<const int4n*>(
                    fi_lr + (fb * W_ + rr) * 2 * P_ + q * 4);
                int4n pxv = *reinterpret_cast<const int4n*>(
                    px_lr + ((fb * C_ + cc) * W_ + rr) * 2 * P_ + q * 4);

                float* obase = out + (size_t)(kk * C_ + cc) * OUTSP
                                   + (size_t)(rr + P_) * W2_ + (q ? (W_ + P_) : 0);
#pragma unroll
                for (int e = 0; e < 4; ++e) {
                    int fe = inv[((const int*)&fiv)[e] + b6];
                    bool own = (fe < 0) ? (phase == 0) : ((fe >> 5) == phase);
                    if (own) {
                        float v = (fe >= 0)
                            ? cube[(size_t)fe * CWW + ((const int*)&pxv)[e]] : 0.0f;
                        __builtin_nontemporal_store(v, obase + e);
                    }
                }
            }
        }
    }
}

extern "C" void kernel_launch(void* const* d_in, const int* in_sizes, int n_in,
                              void* d_out, int out_size, void* d_ws, size_t ws_size,
                              hipStream_t stream) {
    const float* cube         = (const float*)d_in[0];
    const int*   to_process   = (const int*)d_in[1];
    // d_in[2] = batch_size (scalar, fixed = 16)
    const int*   pixel_idx_tb = (const int*)d_in[3];
    const int*   pixel_idx_lr = (const int*)d_in[4];
    const int*   face_idx_tb  = (const int*)d_in[5];
    const int*   face_idx_lr  = (const int*)d_in[6];
    float*       out          = (float*)d_out;

    // Phase 0: faces 0..31 + their halo gathers (and f==-1 zeros).
    fused_pad_phase_kernel<<<2048, 256, 0, stream>>>(
        cube, to_process, pixel_idx_tb, pixel_idx_lr,
        face_idx_tb, face_idx_lr, out, 0);
    // Phase 1: faces 32..63 + their halo gathers.
    fused_pad_phase_kernel<<<2048, 256, 0, stream>>>(
        cube, to_process, pixel_idx_tb, pixel_idx_lr,
        face_idx_tb, face_idx_lr, out, 1);
}

// Round 9
// 220.102 us; speedup vs baseline: 1.4531x; 1.4531x over previous
//
#include <hip/hip_runtime.h>

// Problem constants (fixed by the reference module)
#define K_   64
#define C_   64
#define W_   128
#define P_   4
#define B_   16
#define W2_  136                 // W + 2*PAD
#define OUTSP 18496              // W2*W2 elements per (k,c) plane
#define CWW  1048576             // C*W*W — cube stride per face (k index)

// Face-slot work layout. KEY FACT: to_process is sorted, so all faces of a
// batch are contiguous in k, and every halo gather for output face kk
// targets a cube row within +-5 of kk. Processing halo kk in sync with the
// interior stream at face k==kk makes all gathers hit the L3 sliding window
// (~46 MB), sharing one HBM fetch of the cube between stream and gathers.
//
// Per face slot: 4096 interior units + 528 halo units (272 TB + 256 LR),
// Bresenham-interleaved 528:4624. Unit = 64 lanes x 1 quad (4 floats).
// TB quad layout: [kk][side][cc][rr2][col4]  (8704 quads/(kk,side), 136 u)
// LR quad layout: [kk][side][cc][r]          (8192 quads/(kk,side), 128 u)
#define TB_U_PER_K 272
#define HU_PER_K   528
#define IU_PER_K   4096
#define U_PER_K    4624           // 4096 + 528
#define N_UNITS    (64 * U_PER_K) // 295,936
#define N_WID      (N_UNITS * 64) // 18,939,904 lane-iterations

typedef int   int4n   __attribute__((ext_vector_type(4)));
typedef float float4n __attribute__((ext_vector_type(4)));

__global__ void fused_pad_kernel(const float* __restrict__ cube,
                                 const int* __restrict__ to_process,
                                 const int* __restrict__ px_tb,
                                 const int* __restrict__ px_lr,
                                 const int* __restrict__ fi_tb,
                                 const int* __restrict__ fi_lr,
                                 float* __restrict__ out) {
    __shared__ int inv[6 * B_];   // global face id -> cube row, -1 absent
    __shared__ int tp[K_];
    const int tid = threadIdx.x;
    if (tid < 6 * B_) inv[tid] = -1;
    if (tid < K_)     tp[tid]  = to_process[tid];
    __syncthreads();
    if (tid < K_)     inv[tp[tid]] = tid;
    __syncthreads();

    const int stride = gridDim.x * blockDim.x;
    for (int t = blockIdx.x * blockDim.x + tid; t < N_WID; t += stride) {
        int U = t >> 6;                 // unit (wave-uniform)
        int l = t & 63;                 // lane
        int f = U / U_PER_K;            // face slot 0..63
        int u = U - f * U_PER_K;        // local unit in slot
        int hu  = (u * 33) / 289;       // Bresenham: 528/4624 == 33/289
        bool is_halo = ((u + 1) * 33) / 289 > hu;

        if (!is_halo) {
            // ---- interior: quad id within cube, face f ----
            int iu = u - hu;                         // 0..4095
            int id = ((f * IU_PER_K + iu) << 6) + l; // global quad id
            int q  = id & 31;
            int R  = id >> 5;
            int rr = R & (W_ - 1);
            int kc = R >> 7;
            float4n v = reinterpret_cast<const float4n*>(cube)[id];
            float4n* dst = reinterpret_cast<float4n*>(
                out + (size_t)kc * OUTSP + (size_t)(rr + P_) * W2_ + P_) + q;
            __builtin_nontemporal_store(v, dst);
        } else if (hu < TB_U_PER_K) {
            // ---- TB halo unit for kk == f ----
            int qid  = (f * TB_U_PER_K + hu) * 64 + l;
            int col4 = qid % 34;
            int tq   = qid / 34;
            int rr2  = tq & 3;
            int cc   = (tq >> 2) & 63;
            int side = (tq >> 8) & 1;
            int kk   = tq >> 9;            // == f
            int rr   = side * 4 + rr2;     // 0..7

            int gf = tp[kk];
            int b6 = 6 * (gf / 6);
            int fb = gf - b6;
            int4n fiv = *reinterpret_cast<const int4n*>(
                fi_tb + (fb * 8 + rr) * W2_ + col4 * 4);
            int4n pxv = *reinterpret_cast<const int4n*>(
                px_tb + ((fb * C_ + cc) * 8 + rr) * W2_ + col4 * 4);

            float4n v;
            int f0 = inv[fiv.x + b6];
            int f1 = inv[fiv.y + b6];
            int f2 = inv[fiv.z + b6];
            int f3 = inv[fiv.w + b6];
            v.x = (f0 >= 0) ? cube[(size_t)f0 * CWW + pxv.x] : 0.0f;
            v.y = (f1 >= 0) ? cube[(size_t)f1 * CWW + pxv.y] : 0.0f;
            v.z = (f2 >= 0) ? cube[(size_t)f2 * CWW + pxv.z] : 0.0f;
            v.w = (f3 >= 0) ? cube[(size_t)f3 * CWW + pxv.w] : 0.0f;

            int outr = side ? (W_ + P_ + rr2) : rr2;   // 132+rr2 or rr2
            float4n* dst = reinterpret_cast<float4n*>(
                out + (size_t)(kk * C_ + cc) * OUTSP + (size_t)outr * W2_ + col4 * 4);
            __builtin_nontemporal_store(v, dst);
        } else {
            // ---- LR halo unit for kk == f ----
            int qid  = (f * 256 + (hu - TB_U_PER_K)) * 64 + l;
            int r    = qid & 127;
            int cc   = (qid >> 7) & 63;
            int side = (qid >> 13) & 1;
            int kk   = qid >> 14;          // == f

            int gf = tp[kk];
            int b6 = 6 * (gf / 6);
            int fb = gf - b6;
            int4n fiv = *reinterpret_cast<const int4n*>(
                fi_lr + (fb * W_ + r) * 2 * P_ + side * 4);
            int4n pxv = *reinterpret_cast<const int4n*>(
                px_lr + ((fb * C_ + cc) * W_ + r) * 2 * P_ + side * 4);

            float4n v;
            int f0 = inv[fiv.x + b6];
            int f1 = inv[fiv.y + b6];
            int f2 = inv[fiv.z + b6];
            int f3 = inv[fiv.w + b6];
            v.x = (f0 >= 0) ? cube[(size_t)f0 * CWW + pxv.x] : 0.0f;
            v.y = (f1 >= 0) ? cube[(size_t)f1 * CWW + pxv.y] : 0.0f;
            v.z = (f2 >= 0) ? cube[(size_t)f2 * CWW + pxv.z] : 0.0f;
            v.w = (f3 >= 0) ? cube[(size_t)f3 * CWW + pxv.w] : 0.0f;

            int outc = side ? (W_ + P_) : 0;           // 132 or 0
            float4n* dst = reinterpret_cast<float4n*>(
                out + (size_t)(kk * C_ + cc) * OUTSP + (size_t)(r + P_) * W2_ + outc);
            __builtin_nontemporal_store(v, dst);
        }
    }
}

extern "C" void kernel_launch(void* const* d_in, const int* in_sizes, int n_in,
                              void* d_out, int out_size, void* d_ws, size_t ws_size,
                              hipStream_t stream) {
    const float* cube         = (const float*)d_in[0];
    const int*   to_process   = (const int*)d_in[1];
    // d_in[2] = batch_size (scalar, fixed = 16)
    const int*   pixel_idx_tb = (const int*)d_in[3];
    const int*   pixel_idx_lr = (const int*)d_in[4];
    const int*   face_idx_tb  = (const int*)d_in[5];
    const int*   face_idx_lr  = (const int*)d_in[6];
    float*       out          = (float*)d_out;

    // 2048 blocks x 256 = 8192 units/sweep-step (~1.8 faces); all CUs work
    // the same face region concurrently -> gathers hit the L3 window.
    fused_pad_kernel<<<2048, 256, 0, stream>>>(
        cube, to_process, pixel_idx_tb, pixel_idx_lr,
        face_idx_tb, face_idx_lr, out);
}